// Round 11
// baseline (80.418 us; speedup 1.0000x reference)
//
#include <hip/hip_runtime.h>

#define B_ 16
#define T_ 800
#define D_ 256
#define K_ 64
#define NTILE 13

typedef __attribute__((ext_vector_type(8))) short short8v;
typedef __attribute__((ext_vector_type(4))) float f32x4v;

__device__ __forceinline__ ushort bf16rn(float v) {
    unsigned int b = __float_as_uint(v);
    return (ushort)((b + 0x7fffu + ((b >> 16) & 1u)) >> 16);
}
__device__ __forceinline__ float bf16hi(ushort h) {
    return __uint_as_float(((unsigned int)h) << 16);
}

// ---------------- Fused MFMA kernel (prep merged, 8 waves) ----------------
// grid = 16*13 = 208 blocks x 512 thr (8 waves -> 2/SIMD). Tile 64t x 64k x 256d.
// Phase 1: wave = (tg = w&3 t-16-group, kh = w>>2 k-half); 3-product bf16-split MFMA.
// Softmax over k cross-wave (red_m/red_s). rtT[k][t] bf16 in LDS.
// Transpose xh/xl -> xhT/xlT (reusing mu LDS, XOR-swizzled).
// Phase 2: wave = (kg = w&3 k-16-group, dh = w>>2 d-half); 2-product split MFMA; f32 stores.
__global__ __launch_bounds__(512, 1) void kernelAB(
    const float* __restrict__ x, const float* __restrict__ mu,
    const float* __restrict__ prec,
    float* __restrict__ Pp, float* __restrict__ Spart)
{
    __shared__ ushort xh_s[64 * 264];    // [t][d] pad 264, bf16 hi
    __shared__ ushort xl_s[64 * 264];    // bf16 lo residual
    __shared__ ushort muh_s[64 * 264];   // phase2 reuse: xhT [256 d][64 t] XOR-swizzled
    __shared__ ushort mul_s[64 * 264];   // phase2 reuse: xlT
    __shared__ ushort rtT_s[64 * 72];    // [k][t] pad 72, bf16
    __shared__ float xxs[64], mms[64], p2s[64];
    __shared__ float red_m[64][2], red_s[64][2];
    __shared__ float sred[4][64];

    const int tid  = threadIdx.x;
    const int lane = tid & 63;
    const int w    = tid >> 6;       // 0..7
    const int m    = lane & 15;
    const int q    = lane >> 4;
    const int b    = blockIdx.x / NTILE;
    const int tile = blockIdx.x % NTILE;
    const int t0   = tile * 64;

    if (tid < 64) { float p = prec[tid]; p2s[tid] = p * p; }

    // ---- stage + convert + row-square-reduce: x tile ----
    #pragma unroll 4
    for (int jj = 0; jj < 8; ++jj) {
        const int idx = tid + jj * 512;          // 0..4095 f4
        const int row = idx >> 6;                // = jj*8 + (tid>>6)
        const int cc  = idx & 63;                // = lane
        int trow = t0 + row; if (trow > T_ - 1) trow = T_ - 1;
        float4 v = ((const float4*)x)[(size_t)(b * T_ + trow) * 64 + cc];
        float sq = v.x*v.x + v.y*v.y + v.z*v.z + v.w*v.w;
        #pragma unroll
        for (int off = 32; off > 0; off >>= 1) sq += __shfl_xor(sq, off);
        if (lane == 0) xxs[row] = sq;
        ushort4 h, l;
        h.x = bf16rn(v.x); l.x = bf16rn(v.x - bf16hi(h.x));
        h.y = bf16rn(v.y); l.y = bf16rn(v.y - bf16hi(h.y));
        h.z = bf16rn(v.z); l.z = bf16rn(v.z - bf16hi(h.z));
        h.w = bf16rn(v.w); l.w = bf16rn(v.w - bf16hi(h.w));
        *(ushort4*)&xh_s[row * 264 + cc * 4] = h;
        *(ushort4*)&xl_s[row * 264 + cc * 4] = l;
    }
    // ---- stage + convert + row-square-reduce: mu ----
    #pragma unroll 4
    for (int jj = 0; jj < 8; ++jj) {
        const int idx = tid + jj * 512;
        const int row = idx >> 6, cc = idx & 63;
        float4 v = ((const float4*)mu)[(size_t)row * 64 + cc];
        float sq = v.x*v.x + v.y*v.y + v.z*v.z + v.w*v.w;
        #pragma unroll
        for (int off = 32; off > 0; off >>= 1) sq += __shfl_xor(sq, off);
        if (lane == 0) mms[row] = sq;
        ushort4 h, l;
        h.x = bf16rn(v.x); l.x = bf16rn(v.x - bf16hi(h.x));
        h.y = bf16rn(v.y); l.y = bf16rn(v.y - bf16hi(h.y));
        h.z = bf16rn(v.z); l.z = bf16rn(v.z - bf16hi(h.z));
        h.w = bf16rn(v.w); l.w = bf16rn(v.w - bf16hi(h.w));
        *(ushort4*)&muh_s[row * 264 + cc * 4] = h;
        *(ushort4*)&mul_s[row * 264 + cc * 4] = l;
    }
    __syncthreads();

    // ---- phase 1: dot[t][k]; wave (tg, kh): t = tg*16+.., k = (kh*2+ntl)*16+.. ----
    const int tg = w & 3, kh = w >> 2;
    f32x4v acc[2];
    #pragma unroll
    for (int ntl = 0; ntl < 2; ++ntl) acc[ntl] = (f32x4v){0.f, 0.f, 0.f, 0.f};

    #pragma unroll 2
    for (int c = 0; c < 8; ++c) {
        const int ao = (tg * 16 + m) * 264 + c * 32 + q * 8;
        short8v ah = *(const short8v*)&xh_s[ao];
        short8v al = *(const short8v*)&xl_s[ao];
        #pragma unroll
        for (int ntl = 0; ntl < 2; ++ntl) {
            const int bo = ((kh * 2 + ntl) * 16 + m) * 264 + c * 32 + q * 8;
            short8v bh = *(const short8v*)&muh_s[bo];
            short8v bl = *(const short8v*)&mul_s[bo];
            acc[ntl] = __builtin_amdgcn_mfma_f32_16x16x32_bf16(ah, bh, acc[ntl], 0, 0, 0);
            acc[ntl] = __builtin_amdgcn_mfma_f32_16x16x32_bf16(ah, bl, acc[ntl], 0, 0, 0);
            acc[ntl] = __builtin_amdgcn_mfma_f32_16x16x32_bf16(al, bh, acc[ntl], 0, 0, 0);
        }
    }

    // ---- softmax over k (cross-wave pair kh=0/1). D: row t = q*4+r, col k = m ----
    float p2k[2], mmk[2];
    #pragma unroll
    for (int ntl = 0; ntl < 2; ++ntl) {
        const int kk = (kh * 2 + ntl) * 16 + m;
        p2k[ntl] = p2s[kk]; mmk[ntl] = mms[kk];
    }

    float llk[2][4];
    #pragma unroll
    for (int r = 0; r < 4; ++r) {
        const int tl = tg * 16 + q * 4 + r;
        const float xxv = xxs[tl];
        #pragma unroll
        for (int ntl = 0; ntl < 2; ++ntl)
            llk[ntl][r] = p2k[ntl] * (2.f * acc[ntl][r] - xxv - mmk[ntl]);
    }
    // partial max over this wave's 32 k's
    #pragma unroll
    for (int r = 0; r < 4; ++r) {
        float pm = fmaxf(llk[0][r], llk[1][r]);
        pm = fmaxf(pm, __shfl_xor(pm, 1)); pm = fmaxf(pm, __shfl_xor(pm, 2));
        pm = fmaxf(pm, __shfl_xor(pm, 4)); pm = fmaxf(pm, __shfl_xor(pm, 8));
        if (m == 0) red_m[tg * 16 + q * 4 + r][kh] = pm;
    }
    __syncthreads();
    float e[2][4], psum[4];
    #pragma unroll
    for (int r = 0; r < 4; ++r) {
        const int tl = tg * 16 + q * 4 + r;
        const float gm = fmaxf(red_m[tl][0], red_m[tl][1]);
        float ps = 0.f;
        #pragma unroll
        for (int ntl = 0; ntl < 2; ++ntl) { e[ntl][r] = __expf(llk[ntl][r] - gm); ps += e[ntl][r]; }
        ps += __shfl_xor(ps, 1); ps += __shfl_xor(ps, 2);
        ps += __shfl_xor(ps, 4); ps += __shfl_xor(ps, 8);
        psum[r] = ps;
        if (m == 0) red_s[tl][kh] = ps;
    }
    __syncthreads();
    float sacc[2] = {0.f, 0.f};
    ushort4 rp[2];
    #pragma unroll
    for (int r = 0; r < 4; ++r) {
        const int tl = tg * 16 + q * 4 + r;
        const float gs = red_s[tl][0] + red_s[tl][1];
        const bool valid = (t0 + tl) < T_;
        const float inv = valid ? (1.f / gs) : 0.f;
        #pragma unroll
        for (int ntl = 0; ntl < 2; ++ntl) {
            float rv = e[ntl][r] * inv;
            sacc[ntl] += rv;
            ((ushort*)&rp[ntl])[r] = bf16rn(rv);
        }
    }
    #pragma unroll
    for (int ntl = 0; ntl < 2; ++ntl)
        *(ushort4*)&rtT_s[((kh * 2 + ntl) * 16 + m) * 72 + tg * 16 + q * 4] = rp[ntl];
    #pragma unroll
    for (int ntl = 0; ntl < 2; ++ntl) {
        sacc[ntl] += __shfl_xor(sacc[ntl], 16);
        sacc[ntl] += __shfl_xor(sacc[ntl], 32);
    }
    if (q == 0) {
        #pragma unroll
        for (int ntl = 0; ntl < 2; ++ntl)
            sred[tg][(kh * 2 + ntl) * 16 + m] = sacc[ntl];
    }
    __syncthreads();   // rtT + sred ready; all phase-1 muh/mul reads complete

    if (tid < 64) {
        float s = sred[0][tid] + sred[1][tid] + sred[2][tid] + sred[3][tid];
        Spart[((size_t)b * NTILE + tile) * K_ + tid] = s;
    }

    // ---- transpose xh/xl -> xhT/xlT over muh_s/mul_s; same-typed ushort2 stores ----
    {
        const int tp = tid & 31, dg = tid >> 5;   // t-pair, 16-d group (dg 0..15)
        #pragma unroll
        for (int c = 0; c < 2; ++c) {
            short8v a0 = *(const short8v*)&xh_s[(2 * tp)     * 264 + dg * 16 + c * 8];
            short8v a1 = *(const short8v*)&xh_s[(2 * tp + 1) * 264 + dg * 16 + c * 8];
            short8v b0 = *(const short8v*)&xl_s[(2 * tp)     * 264 + dg * 16 + c * 8];
            short8v b1 = *(const short8v*)&xl_s[(2 * tp + 1) * 264 + dg * 16 + c * 8];
            #pragma unroll
            for (int j = 0; j < 8; ++j) {
                const int d = dg * 16 + c * 8 + j;
                const int widx = (tp & 3) + 4 * ((tp >> 2) ^ (d & 7));
                ushort2 hv, lv;
                hv.x = (ushort)a0[j]; hv.y = (ushort)a1[j];
                lv.x = (ushort)b0[j]; lv.y = (ushort)b1[j];
                *(ushort2*)&muh_s[d * 64 + widx * 2] = hv;
                *(ushort2*)&mul_s[d * 64 + widx * 2] = lv;
            }
        }
    }
    __syncthreads();

    // ---- phase 2: P[k][d]; wave (kg = w&3, dh = w>>2): k = kg*16+.., d-half dh ----
    const int kg = w & 3, dh = w >> 2;
    f32x4v acc2[8];
    #pragma unroll
    for (int ntl = 0; ntl < 8; ++ntl) acc2[ntl] = (f32x4v){0.f, 0.f, 0.f, 0.f};

    #pragma unroll
    for (int tc = 0; tc < 2; ++tc) {
        short8v ar = *(const short8v*)&rtT_s[(kg * 16 + m) * 72 + tc * 32 + q * 8];
        #pragma unroll
        for (int ntl = 0; ntl < 8; ++ntl) {
            const int drow = (dh * 8 + ntl) * 16 + m;
            const int eoff = ((tc * 4 + q) ^ (drow & 7)) * 8;
            short8v bh = *(const short8v*)&muh_s[drow * 64 + eoff];
            short8v bl = *(const short8v*)&mul_s[drow * 64 + eoff];
            acc2[ntl] = __builtin_amdgcn_mfma_f32_16x16x32_bf16(ar, bh, acc2[ntl], 0, 0, 0);
            acc2[ntl] = __builtin_amdgcn_mfma_f32_16x16x32_bf16(ar, bl, acc2[ntl], 0, 0, 0);
        }
    }

    float* Pb = Pp + ((size_t)(b * NTILE + tile)) * K_ * D_;
    #pragma unroll
    for (int ntl = 0; ntl < 8; ++ntl) {
        #pragma unroll
        for (int r = 0; r < 4; ++r)
            Pb[(size_t)(kg * 16 + q * 4 + r) * D_ + (dh * 8 + ntl) * 16 + m] = acc2[ntl][r];
    }
}

// ---------------- Kernel C: out = (sum_tile Pp)*inv - (S*inv)*mu ----------------
__global__ __launch_bounds__(256) void kernelC(
    const float* __restrict__ Pp, const float* __restrict__ Spart,
    const float* __restrict__ mu, float* __restrict__ out)
{
    const int o4 = blockIdx.x * 256 + threadIdx.x;   // ((b*64+k)*64+d4)
    const int d4 = o4 & 63;
    const int k  = (o4 >> 6) & 63;
    const int b  = o4 >> 12;

    float s = 0.f;
    #pragma unroll
    for (int p = 0; p < NTILE; ++p)
        s += Spart[((size_t)b * NTILE + p) * K_ + k];

    float4 acc = make_float4(0.f, 0.f, 0.f, 0.f);
    #pragma unroll
    for (int p = 0; p < NTILE; ++p) {
        float4 v = ((const float4*)Pp)[((size_t)(b * NTILE + p) * K_ + k) * (D_ / 4) + d4];
        acc.x += v.x; acc.y += v.y; acc.z += v.z; acc.w += v.w;
    }
    const float inv = 1.f / (s + 1e-9f);
    const float sm  = s * inv;
    const float4 m = ((const float4*)mu)[k * 64 + d4];
    float4 o;
    o.x = acc.x * inv - sm * m.x;
    o.y = acc.y * inv - sm * m.y;
    o.z = acc.z * inv - sm * m.z;
    o.w = acc.w * inv - sm * m.w;
    ((float4*)out)[o4] = o;
}

extern "C" void kernel_launch(void* const* d_in, const int* in_sizes, int n_in,
                              void* d_out, int out_size, void* d_ws, size_t ws_size,
                              hipStream_t stream) {
    const float* x    = (const float*)d_in[0];
    const float* mu   = (const float*)d_in[1];
    const float* prec = (const float*)d_in[2];
    float* out = (float*)d_out;

    float* Pp    = (float*)d_ws;                       // 208*64*256 f = 13.6 MB
    float* Spart = Pp + (size_t)B_ * NTILE * K_ * D_;  // 13312 f

    kernelAB<<<B_ * NTILE, 512, 0, stream>>>(x, mu, prec, Pp, Spart);
    kernelC<<<256, 256, 0, stream>>>(Pp, Spart, mu, out);
}

// Round 12
// 79.442 us; speedup vs baseline: 1.0123x; 1.0123x over previous
//
#include <hip/hip_runtime.h>

#define B_ 16
#define T_ 800
#define D_ 256
#define K_ 64
#define NTILE 13

typedef __attribute__((ext_vector_type(8))) short short8v;
typedef __attribute__((ext_vector_type(4))) float f32x4v;

__device__ __forceinline__ ushort bf16rn(float v) {
    unsigned int b = __float_as_uint(v);
    return (ushort)((b + 0x7fffu + ((b >> 16) & 1u)) >> 16);
}
__device__ __forceinline__ float bf16hi(ushort h) {
    return __uint_as_float(((unsigned int)h) << 16);
}

// ---------------- Fused MFMA kernel (prep merged, 8 waves) ----------------
// grid = 16*13 = 208 blocks x 512 thr (8 waves -> 2/SIMD). Tile 64t x 64k x 256d.
// Phase 1: wave = (tg = w&3 t-16-group, kh = w>>2 k-half); 3-product bf16-split MFMA.
// Softmax over k cross-wave (red_m/red_s). rtT[k][t] bf16 in LDS.
// Transpose xh/xl -> xhT/xlT (reusing mu LDS, XOR-swizzled).
// Phase 2: wave = (kg = w&3, dh = w>>2); 2-product split MFMA; bf16 stores to Pp.
__global__ __launch_bounds__(512, 1) void kernelAB(
    const float* __restrict__ x, const float* __restrict__ mu,
    const float* __restrict__ prec,
    ushort* __restrict__ Pp, float* __restrict__ Spart)
{
    __shared__ ushort xh_s[64 * 264];    // [t][d] pad 264, bf16 hi
    __shared__ ushort xl_s[64 * 264];    // bf16 lo residual
    __shared__ ushort muh_s[64 * 264];   // phase2 reuse: xhT [256 d][64 t] XOR-swizzled
    __shared__ ushort mul_s[64 * 264];   // phase2 reuse: xlT
    __shared__ ushort rtT_s[64 * 72];    // [k][t] pad 72, bf16
    __shared__ float xxs[64], mms[64], p2s[64];
    __shared__ float red_m[64][2], red_s[64][2];
    __shared__ float sred[4][64];

    const int tid  = threadIdx.x;
    const int lane = tid & 63;
    const int w    = tid >> 6;       // 0..7
    const int m    = lane & 15;
    const int q    = lane >> 4;
    const int b    = blockIdx.x / NTILE;
    const int tile = blockIdx.x % NTILE;
    const int t0   = tile * 64;

    if (tid < 64) { float p = prec[tid]; p2s[tid] = p * p; }

    // ---- stage + convert + row-square-reduce: x tile ----
    #pragma unroll 4
    for (int jj = 0; jj < 8; ++jj) {
        const int idx = tid + jj * 512;          // 0..4095 f4
        const int row = idx >> 6;
        const int cc  = idx & 63;                // = lane
        int trow = t0 + row; if (trow > T_ - 1) trow = T_ - 1;
        float4 v = ((const float4*)x)[(size_t)(b * T_ + trow) * 64 + cc];
        float sq = v.x*v.x + v.y*v.y + v.z*v.z + v.w*v.w;
        #pragma unroll
        for (int off = 32; off > 0; off >>= 1) sq += __shfl_xor(sq, off);
        if (lane == 0) xxs[row] = sq;
        ushort4 h, l;
        h.x = bf16rn(v.x); l.x = bf16rn(v.x - bf16hi(h.x));
        h.y = bf16rn(v.y); l.y = bf16rn(v.y - bf16hi(h.y));
        h.z = bf16rn(v.z); l.z = bf16rn(v.z - bf16hi(h.z));
        h.w = bf16rn(v.w); l.w = bf16rn(v.w - bf16hi(h.w));
        *(ushort4*)&xh_s[row * 264 + cc * 4] = h;
        *(ushort4*)&xl_s[row * 264 + cc * 4] = l;
    }
    // ---- stage + convert + row-square-reduce: mu ----
    #pragma unroll 4
    for (int jj = 0; jj < 8; ++jj) {
        const int idx = tid + jj * 512;
        const int row = idx >> 6, cc = idx & 63;
        float4 v = ((const float4*)mu)[(size_t)row * 64 + cc];
        float sq = v.x*v.x + v.y*v.y + v.z*v.z + v.w*v.w;
        #pragma unroll
        for (int off = 32; off > 0; off >>= 1) sq += __shfl_xor(sq, off);
        if (lane == 0) mms[row] = sq;
        ushort4 h, l;
        h.x = bf16rn(v.x); l.x = bf16rn(v.x - bf16hi(h.x));
        h.y = bf16rn(v.y); l.y = bf16rn(v.y - bf16hi(h.y));
        h.z = bf16rn(v.z); l.z = bf16rn(v.z - bf16hi(h.z));
        h.w = bf16rn(v.w); l.w = bf16rn(v.w - bf16hi(h.w));
        *(ushort4*)&muh_s[row * 264 + cc * 4] = h;
        *(ushort4*)&mul_s[row * 264 + cc * 4] = l;
    }
    __syncthreads();

    // ---- phase 1: dot[t][k]; wave (tg, kh): t = tg*16+.., k = (kh*2+ntl)*16+.. ----
    const int tg = w & 3, kh = w >> 2;
    f32x4v acc[2];
    #pragma unroll
    for (int ntl = 0; ntl < 2; ++ntl) acc[ntl] = (f32x4v){0.f, 0.f, 0.f, 0.f};

    #pragma unroll 2
    for (int c = 0; c < 8; ++c) {
        const int ao = (tg * 16 + m) * 264 + c * 32 + q * 8;
        short8v ah = *(const short8v*)&xh_s[ao];
        short8v al = *(const short8v*)&xl_s[ao];
        #pragma unroll
        for (int ntl = 0; ntl < 2; ++ntl) {
            const int bo = ((kh * 2 + ntl) * 16 + m) * 264 + c * 32 + q * 8;
            short8v bh = *(const short8v*)&muh_s[bo];
            short8v bl = *(const short8v*)&mul_s[bo];
            acc[ntl] = __builtin_amdgcn_mfma_f32_16x16x32_bf16(ah, bh, acc[ntl], 0, 0, 0);
            acc[ntl] = __builtin_amdgcn_mfma_f32_16x16x32_bf16(ah, bl, acc[ntl], 0, 0, 0);
            acc[ntl] = __builtin_amdgcn_mfma_f32_16x16x32_bf16(al, bh, acc[ntl], 0, 0, 0);
        }
    }

    // ---- softmax over k (cross-wave pair kh=0/1). D: row t = q*4+r, col k = m ----
    float p2k[2], mmk[2];
    #pragma unroll
    for (int ntl = 0; ntl < 2; ++ntl) {
        const int kk = (kh * 2 + ntl) * 16 + m;
        p2k[ntl] = p2s[kk]; mmk[ntl] = mms[kk];
    }

    float llk[2][4];
    #pragma unroll
    for (int r = 0; r < 4; ++r) {
        const int tl = tg * 16 + q * 4 + r;
        const float xxv = xxs[tl];
        #pragma unroll
        for (int ntl = 0; ntl < 2; ++ntl)
            llk[ntl][r] = p2k[ntl] * (2.f * acc[ntl][r] - xxv - mmk[ntl]);
    }
    #pragma unroll
    for (int r = 0; r < 4; ++r) {
        float pm = fmaxf(llk[0][r], llk[1][r]);
        pm = fmaxf(pm, __shfl_xor(pm, 1)); pm = fmaxf(pm, __shfl_xor(pm, 2));
        pm = fmaxf(pm, __shfl_xor(pm, 4)); pm = fmaxf(pm, __shfl_xor(pm, 8));
        if (m == 0) red_m[tg * 16 + q * 4 + r][kh] = pm;
    }
    __syncthreads();
    float e[2][4];
    #pragma unroll
    for (int r = 0; r < 4; ++r) {
        const int tl = tg * 16 + q * 4 + r;
        const float gm = fmaxf(red_m[tl][0], red_m[tl][1]);
        float ps = 0.f;
        #pragma unroll
        for (int ntl = 0; ntl < 2; ++ntl) { e[ntl][r] = __expf(llk[ntl][r] - gm); ps += e[ntl][r]; }
        ps += __shfl_xor(ps, 1); ps += __shfl_xor(ps, 2);
        ps += __shfl_xor(ps, 4); ps += __shfl_xor(ps, 8);
        if (m == 0) red_s[tl][kh] = ps;
    }
    __syncthreads();
    float sacc[2] = {0.f, 0.f};
    ushort4 rp[2];
    #pragma unroll
    for (int r = 0; r < 4; ++r) {
        const int tl = tg * 16 + q * 4 + r;
        const float gs = red_s[tl][0] + red_s[tl][1];
        const bool valid = (t0 + tl) < T_;
        const float inv = valid ? (1.f / gs) : 0.f;
        #pragma unroll
        for (int ntl = 0; ntl < 2; ++ntl) {
            float rv = e[ntl][r] * inv;
            sacc[ntl] += rv;
            ((ushort*)&rp[ntl])[r] = bf16rn(rv);
        }
    }
    #pragma unroll
    for (int ntl = 0; ntl < 2; ++ntl)
        *(ushort4*)&rtT_s[((kh * 2 + ntl) * 16 + m) * 72 + tg * 16 + q * 4] = rp[ntl];
    #pragma unroll
    for (int ntl = 0; ntl < 2; ++ntl) {
        sacc[ntl] += __shfl_xor(sacc[ntl], 16);
        sacc[ntl] += __shfl_xor(sacc[ntl], 32);
    }
    if (q == 0) {
        #pragma unroll
        for (int ntl = 0; ntl < 2; ++ntl)
            sred[tg][(kh * 2 + ntl) * 16 + m] = sacc[ntl];
    }
    __syncthreads();   // rtT + sred ready; all phase-1 muh/mul reads complete

    if (tid < 64) {
        float s = sred[0][tid] + sred[1][tid] + sred[2][tid] + sred[3][tid];
        Spart[((size_t)b * NTILE + tile) * K_ + tid] = s;
    }

    // ---- transpose xh/xl -> xhT/xlT over muh_s/mul_s; same-typed ushort2 stores ----
    {
        const int tp = tid & 31, dg = tid >> 5;   // t-pair, 16-d group
        #pragma unroll
        for (int c = 0; c < 2; ++c) {
            short8v a0 = *(const short8v*)&xh_s[(2 * tp)     * 264 + dg * 16 + c * 8];
            short8v a1 = *(const short8v*)&xh_s[(2 * tp + 1) * 264 + dg * 16 + c * 8];
            short8v b0 = *(const short8v*)&xl_s[(2 * tp)     * 264 + dg * 16 + c * 8];
            short8v b1 = *(const short8v*)&xl_s[(2 * tp + 1) * 264 + dg * 16 + c * 8];
            #pragma unroll
            for (int j = 0; j < 8; ++j) {
                const int d = dg * 16 + c * 8 + j;
                const int widx = (tp & 3) + 4 * ((tp >> 2) ^ (d & 7));
                ushort2 hv, lv;
                hv.x = (ushort)a0[j]; hv.y = (ushort)a1[j];
                lv.x = (ushort)b0[j]; lv.y = (ushort)b1[j];
                *(ushort2*)&muh_s[d * 64 + widx * 2] = hv;
                *(ushort2*)&mul_s[d * 64 + widx * 2] = lv;
            }
        }
    }
    __syncthreads();

    // ---- phase 2: P[k][d]; wave (kg = w&3, dh = w>>2) ----
    const int kg = w & 3, dh = w >> 2;
    f32x4v acc2[8];
    #pragma unroll
    for (int ntl = 0; ntl < 8; ++ntl) acc2[ntl] = (f32x4v){0.f, 0.f, 0.f, 0.f};

    #pragma unroll
    for (int tc = 0; tc < 2; ++tc) {
        short8v ar = *(const short8v*)&rtT_s[(kg * 16 + m) * 72 + tc * 32 + q * 8];
        #pragma unroll
        for (int ntl = 0; ntl < 8; ++ntl) {
            const int drow = (dh * 8 + ntl) * 16 + m;
            const int eoff = ((tc * 4 + q) ^ (drow & 7)) * 8;
            short8v bh = *(const short8v*)&muh_s[drow * 64 + eoff];
            short8v bl = *(const short8v*)&mul_s[drow * 64 + eoff];
            acc2[ntl] = __builtin_amdgcn_mfma_f32_16x16x32_bf16(ar, bh, acc2[ntl], 0, 0, 0);
            acc2[ntl] = __builtin_amdgcn_mfma_f32_16x16x32_bf16(ar, bl, acc2[ntl], 0, 0, 0);
        }
    }

    // store bf16: Pp[((b*13+tile)*64 + k)*256 + d]
    ushort* Pb = Pp + ((size_t)(b * NTILE + tile)) * K_ * D_;
    #pragma unroll
    for (int ntl = 0; ntl < 8; ++ntl) {
        #pragma unroll
        for (int r = 0; r < 4; ++r)
            Pb[(size_t)(kg * 16 + q * 4 + r) * D_ + (dh * 8 + ntl) * 16 + m] =
                bf16rn(acc2[ntl][r]);
    }
}

// ---------------- Kernel C: out = (sum_tile Pp)*inv - (S*inv)*mu ----------------
__global__ __launch_bounds__(256) void kernelC(
    const ushort* __restrict__ Pp, const float* __restrict__ Spart,
    const float* __restrict__ mu, float* __restrict__ out)
{
    const int o4 = blockIdx.x * 256 + threadIdx.x;   // ((b*64+k)*64+d4)
    const int d4 = o4 & 63;
    const int k  = (o4 >> 6) & 63;
    const int b  = o4 >> 12;

    float s = 0.f;
    #pragma unroll
    for (int p = 0; p < NTILE; ++p)
        s += Spart[((size_t)b * NTILE + p) * K_ + k];

    float4 acc = make_float4(0.f, 0.f, 0.f, 0.f);
    #pragma unroll
    for (int p = 0; p < NTILE; ++p) {
        ushort4 v = *(const ushort4*)&Pp[(((size_t)(b * NTILE + p)) * K_ + k) * D_ + d4 * 4];
        acc.x += bf16hi(v.x); acc.y += bf16hi(v.y);
        acc.z += bf16hi(v.z); acc.w += bf16hi(v.w);
    }
    const float inv = 1.f / (s + 1e-9f);
    const float sm  = s * inv;
    const float4 m = ((const float4*)mu)[k * 64 + d4];
    float4 o;
    o.x = acc.x * inv - sm * m.x;
    o.y = acc.y * inv - sm * m.y;
    o.z = acc.z * inv - sm * m.z;
    o.w = acc.w * inv - sm * m.w;
    ((float4*)out)[o4] = o;
}

extern "C" void kernel_launch(void* const* d_in, const int* in_sizes, int n_in,
                              void* d_out, int out_size, void* d_ws, size_t ws_size,
                              hipStream_t stream) {
    const float* x    = (const float*)d_in[0];
    const float* mu   = (const float*)d_in[1];
    const float* prec = (const float*)d_in[2];
    float* out = (float*)d_out;

    ushort* Pp   = (ushort*)d_ws;                          // 208*64*256 u16 = 6.8 MB
    float* Spart = (float*)(Pp + (size_t)B_ * NTILE * K_ * D_);  // 13312 f

    kernelAB<<<B_ * NTILE, 512, 0, stream>>>(x, mu, prec, Pp, Spart);
    kernelC<<<256, 256, 0, stream>>>(Pp, Spart, mu, out);
}